// Round 16
// baseline (98.014 us; speedup 1.0000x reference)
//
#include <hip/hip_runtime.h>
#include <hip/hip_bf16.h>
#include <math.h>

#define B_N    32768
#define XD     60
#define YD     10
#define NK     64
#define HID    2048
#define OUTD   704   // NK + NK*YD
#define TS     128   // rows per tile
#define MAXT   320   // >= 256 full tiles + 64 partials; divisible by 8 (XCD swizzle)
#define NSLAB  32    // 64-hid slabs

#define LBLK   128   // label blocks (B/256)

typedef __bf16 bf16x8_t __attribute__((ext_vector_type(8)));
typedef float  f32x4_t  __attribute__((ext_vector_type(4)));

union Frag { uint4 q; bf16x8_t v; };

#define MFMA16(a, b, c) __builtin_amdgcn_mfma_f32_16x16x32_bf16(a, b, c, 0, 0, 0)
#define GLOAD(gsrc, ldst) \
    __builtin_amdgcn_global_load_lds((const __attribute__((address_space(1))) unsigned int*)(gsrc), \
                                     (__attribute__((address_space(3))) unsigned int*)(ldst), 16, 0, 0)

__device__ __forceinline__ unsigned short bf16bits(float f) {
    __hip_bfloat16 h = __float2bfloat16(f);
    return *reinterpret_cast<unsigned short*>(&h);
}

// ---------------- merged prep: labels+counts | W1P | W2P | W2G packs ----------
// Fragment-major packing: slice f covers hid [32f,32f+32).
// W1P rec (4f+j)*512 shorts, j=n2*2+ks; row k==60 holds b1 (bias fold).
// W2P rec (4f+nt)*512; W2G rec (64g+f)*512.
__global__ __launch_bounds__(256) void k_prep(const float* __restrict__ y,
                                              const float* __restrict__ centers,
                                              const float* __restrict__ W1,
                                              const float* __restrict__ b1,
                                              const float* __restrict__ W2,
                                              int* __restrict__ labels,
                                              int* __restrict__ counts,
                                              unsigned short* __restrict__ W1P,
                                              unsigned short* __restrict__ W2P,
                                              unsigned short* __restrict__ W2G) {
    __shared__ __align__(16) char smem[40960];
    int bid = blockIdx.x, t = threadIdx.x;
    int l  = t & 63;
    int lr = l & 15;
    int lg = l >> 4;

    if (bid < LBLK) {
        float* cs = (float*)smem; float* sc = cs + 640; int* lh = (int*)(cs + 704);
        for (int i = t; i < NK * YD; i += 256) cs[i] = centers[i];
        if (t < NK) lh[t] = 0;
        __syncthreads();
        if (t < NK) { float s = 0.f; for (int j = 0; j < YD; ++j) { float v = cs[t*YD+j]; s += v*v; } sc[t] = s; }
        __syncthreads();
        int i = bid * 256 + t;
        float ly[YD]; float sy = 0.f;
        for (int j = 0; j < YD; ++j) { ly[j] = y[i*YD+j]; sy += ly[j]*ly[j]; }
        float best = 1e30f; int lab = 0;
        for (int k = 0; k < NK; ++k) {
            float dot = 0.f;
            #pragma unroll
            for (int j = 0; j < YD; ++j) dot += ly[j] * cs[k*YD+j];
            float d = sy - 2.f*dot + sc[k];
            if (d < best) { best = d; lab = k; }
        }
        labels[i] = lab;
        atomicAdd(&lh[lab], 1);
        __syncthreads();
        if (t < NK && lh[t] > 0) atomicAdd(&counts[t], lh[t]);
    } else if (bid < LBLK + 64) {
        int b = bid - LBLK, s = b >> 2, w = b & 3;   // f = 4s+w
        unsigned short (*lds)[32] = (unsigned short(*)[32])smem;
        int n0 = 128*s + 32*w;
        for (int idx = t; idx < 64*32; idx += 256) {
            int kk = idx >> 5, c = idx & 31;
            float v = (kk < XD) ? W1[(size_t)(YD + kk) * HID + n0 + c]
                                : ((kk == XD) ? b1[n0 + c] : 0.f);   // bias fold at k=60
            lds[kk][c] = bf16bits(v);
        }
        __syncthreads();
        int n2 = t >> 7, ks = (t >> 6) & 1;
        ushort2 o[4];
        #pragma unroll
        for (int jj = 0; jj < 4; ++jj) {
            o[jj].x = lds[32*ks + 8*lg + 2*jj    ][16*n2 + lr];
            o[jj].y = lds[32*ks + 8*lg + 2*jj + 1][16*n2 + lr];
        }
        *reinterpret_cast<uint4*>(&W1P[((((s*4 + w)*2 + n2)*2 + ks) << 9) + l*8]) =
            *reinterpret_cast<uint4*>(o);
    } else if (bid < LBLK + 128) {
        int b = bid - LBLK - 64, s = b >> 2, w = b & 3;
        unsigned short (*lds)[64] = (unsigned short(*)[64])smem;
        int k0 = 128*s + 32*w;
        for (int idx = t; idx < 32*64; idx += 256) {
            int kk = idx >> 6, c = idx & 63;
            lds[kk][c] = bf16bits(W2[(size_t)(k0 + kk) * OUTD + c]);
        }
        __syncthreads();
        int nt = t >> 6;
        ushort2 o[4];
        #pragma unroll
        for (int jj = 0; jj < 4; ++jj) {
            o[jj].x = lds[8*lg + 2*jj    ][16*nt + lr];
            o[jj].y = lds[8*lg + 2*jj + 1][16*nt + lr];
        }
        *reinterpret_cast<uint4*>(&W2P[(((s*4 + w)*4 + nt) << 9) + l*8]) =
            *reinterpret_cast<uint4*>(o);
    } else {
        int b = bid - LBLK - 128, s = b >> 2, w = b & 3;
        unsigned short (*lds)[640] = (unsigned short(*)[640])smem;
        int k0 = 128*s + 32*w;
        for (int idx = t; idx < 32*640; idx += 256) {
            int kk = idx / 640, c = idx - kk*640;
            lds[kk][c] = bf16bits(W2[(size_t)(k0 + kk) * OUTD + NK + c]);
        }
        __syncthreads();
        for (int g = t >> 6; g < 64; g += 4) {
            ushort2 o[4];
            #pragma unroll
            for (int jj = 0; jj < 4; ++jj) {
                o[jj].x = (lr < YD) ? lds[8*lg + 2*jj    ][10*g + lr] : (unsigned short)0;
                o[jj].y = (lr < YD) ? lds[8*lg + 2*jj + 1][10*g + lr] : (unsigned short)0;
            }
            *reinterpret_cast<uint4*>(&W2G[(((g*16 + s)*4 + w) << 9) + l*8]) =
                *reinterpret_cast<uint4*>(o);
        }
    }
}

// ---------------- wave-parallel scan + tile-descriptor build ----------
__global__ void k_scan(const int* __restrict__ counts, int* __restrict__ cursor,
                       int* __restrict__ tile_g, int* __restrict__ tile_off,
                       int* __restrict__ tile_n) {
    int t = threadIdx.x;
    int c = counts[t];
    int ntm = (c + TS - 1) / TS;
    int sc = c, st = ntm;
    #pragma unroll
    for (int d = 1; d < 64; d <<= 1) {
        int vc = __shfl_up(sc, d);
        int vt = __shfl_up(st, d);
        if (t >= d) { sc += vc; st += vt; }
    }
    int off   = sc - c;
    int tbase = st - ntm;
    cursor[t] = off;
    for (int i = 0; i < ntm; ++i) {
        tile_g[tbase + i]   = t;
        tile_off[tbase + i] = off + TS * i;
        tile_n[tbase + i]   = min(TS, c - TS * i);
    }
    int total = __shfl(st, 63);
    for (int i = total + t; i < MAXT; i += 64) tile_n[i] = 0;
}

// ---------------- scatter ----------
__global__ __launch_bounds__(256) void k_scatter(const int* __restrict__ labels,
                                                 int* __restrict__ cursor,
                                                 int* __restrict__ perm) {
    __shared__ int lh[NK], lbase[NK];
    int t = threadIdx.x;
    if (t < NK) lh[t] = 0;
    __syncthreads();
    int i = blockIdx.x * 256 + t;
    int lab = labels[i];
    int rank = atomicAdd(&lh[lab], 1);
    __syncthreads();
    if (t < NK && lh[t] > 0) lbase[t] = atomicAdd(&cursor[t], lh[t]);
    __syncthreads();
    perm[lbase[lab] + rank] = i;
}

// ---------------- fused: one 128-row single-group tile per block, 4 waves
// ROW-SPLIT (wave w owns rows 32w..32w+31, full hid). Per 64-hid slab the
// block stages 18 x 1KB weight records into a double-buffered LDS wbuf via
// global_load_lds (no VGPR staging); 1 barrier/slab; stage(s+1) drains at
// the NEXT slab's barrier -> 1-slab-deep pipeline (m97 structure).
__global__ __launch_bounds__(256, 2) void k_fused(const float* __restrict__ x,
                                                  const unsigned short* __restrict__ W1P,
                                                  const unsigned short* __restrict__ W2P,
                                                  const unsigned short* __restrict__ W2G,
                                                  const float* __restrict__ b2,
                                                  const float* __restrict__ y,
                                                  const float* __restrict__ centers,
                                                  const int* __restrict__ tile_g,
                                                  const int* __restrict__ tile_off,
                                                  const int* __restrict__ tile_n,
                                                  const int* __restrict__ perm,
                                                  float* __restrict__ accum) {
    __shared__ __align__(16) union {
        struct {
            unsigned short x[TS][80];          // 20480 B
            uint2 h[4][32][18];                // 18432 B (per-wave h scratch, 144B pitch)
            unsigned short wbuf[2][18 * 512];  // 36864 B (double-buffered weight records)
        } a;
        float o[TS][84];                       // 43008 B (epilogue overlay)
    } u;
    __shared__ int   rows_s[TS];
    __shared__ float red_ce[TS], red_mse[TS];

    int phys = blockIdx.x, t = threadIdx.x;
    int bid  = (phys & 7) * (MAXT / 8) + (phys >> 3);   // XCD chunk swizzle (bijective)
    int nrows = tile_n[bid];
    if (nrows == 0) return;
    int g   = tile_g[bid];
    int off = tile_off[bid];

    int w  = t >> 6;          // wave 0..3 (owns rows 32w..32w+31)
    int l  = t & 63;
    int lr = l & 15;
    int lg = l >> 4;

    if (t < TS) rows_s[t] = (t < nrows) ? perm[off + t] : -1;
    __syncthreads();

    // ---- stage slab 0 into wbuf[0] (overlaps the x-gather below)
    {
        int S = 0;
        for (int i = w; i < 18; i += 4) {
            const unsigned short* src; int gofs;
            if (i < 8)       { int q = i >> 1, kh = i & 1; src = W1P; gofs = (4*(2*S + (q>>1)) + ((q&1)*2 + kh)) << 9; }
            else if (i < 16) { int j = i - 8, kh = j >> 2, nt = j & 3; src = W2P; gofs = (4*(2*S + kh) + nt) << 9; }
            else             { int kh = i & 1; src = W2G; gofs = (64*g + 2*S + kh) << 9; }
            GLOAD(src + gofs + l*8, &u.a.wbuf[0][i*512]);
        }
    }

    // ---- gather x rows -> LDS bf16 (vectorized); col 60 = 1.0 (bias), 61..79 = 0
    {
        int c4 = t & 15;
        #pragma unroll
        for (int it = 0; it < 8; ++it) {
            int r = 16 * it + (t >> 4);
            int row = rows_s[r];
            if (c4 < 15) {
                ushort4 pk = {0, 0, 0, 0};
                if (row >= 0) {
                    float4 v = *reinterpret_cast<const float4*>(&x[(size_t)row * XD + 4 * c4]);
                    pk.x = bf16bits(v.x); pk.y = bf16bits(v.y);
                    pk.z = bf16bits(v.z); pk.w = bf16bits(v.w);
                }
                *reinterpret_cast<ushort4*>(&u.a.x[r][4 * c4]) = pk;
            } else {
                ushort4 b = {0, 0, 0, 0};
                b.x = (row >= 0) ? (unsigned short)0x3F80 : (unsigned short)0;  // bf16 1.0
                *reinterpret_cast<ushort4*>(&u.a.x[r][60]) = b;
                ushort4 z = {0, 0, 0, 0};
                *reinterpret_cast<ushort4*>(&u.a.x[r][64]) = z;
                *reinterpret_cast<ushort4*>(&u.a.x[r][68]) = z;
                *reinterpret_cast<ushort4*>(&u.a.x[r][72]) = z;
                *reinterpret_cast<ushort4*>(&u.a.x[r][76]) = z;
            }
        }
    }
    __syncthreads();   // gather + stage(0) drained

    // x fragments for this wave's 32 rows (slab-invariant)
    Frag xf[2][2];
    #pragma unroll
    for (int mt = 0; mt < 2; ++mt)
        #pragma unroll
        for (int ks = 0; ks < 2; ++ks)
            xf[mt][ks].q = *reinterpret_cast<const uint4*>(&u.a.x[32*w + 16*mt + lr][32*ks + 8*lg]);

    f32x4_t acc2[2][5];
    #pragma unroll
    for (int mt = 0; mt < 2; ++mt)
        #pragma unroll
        for (int nt = 0; nt < 5; ++nt) acc2[mt][nt] = (f32x4_t){0.f, 0.f, 0.f, 0.f};

    uint2* hw = &u.a.h[w][0][0];

    for (int s = 0; s < NSLAB; ++s) {
        __syncthreads();   // all waves done reading wbuf[(s+1)&1] (slab s-1); stage(s) drained
        // ---- stage slab s+1 into the buffer just freed
        if (s + 1 < NSLAB) {
            int S = s + 1, pb = (s + 1) & 1;
            for (int i = w; i < 18; i += 4) {
                const unsigned short* src; int gofs;
                if (i < 8)       { int q = i >> 1, kh = i & 1; src = W1P; gofs = (4*(2*S + (q>>1)) + ((q&1)*2 + kh)) << 9; }
                else if (i < 16) { int j = i - 8, kh = j >> 2, nt = j & 3; src = W2P; gofs = (4*(2*S + kh) + nt) << 9; }
                else             { int kh = i & 1; src = W2G; gofs = (64*g + 2*S + kh) << 9; }
                GLOAD(src + gofs + l*8, &u.a.wbuf[pb][i*512]);
            }
        }
        // ---- compute slab s from wbuf[s&1]
        const unsigned short* wb = &u.a.wbuf[s & 1][0];
        // GEMM1 (swapped): 64 hid cols, rows 32w..32w+31; pack -> per-wave h scratch
        #pragma unroll
        for (int mt = 0; mt < 2; ++mt) {
            #pragma unroll
            for (int q = 0; q < 4; ++q) {          // hid quadrant 16q..16q+15
                Frag w0, w1;
                w0.q = *reinterpret_cast<const uint4*>(&wb[(q*2    ) * 512 + l*8]);
                w1.q = *reinterpret_cast<const uint4*>(&wb[(q*2 + 1) * 512 + l*8]);
                f32x4_t hq = {0.f, 0.f, 0.f, 0.f};
                hq = MFMA16(w0.v, xf[mt][0].v, hq);
                hq = MFMA16(w1.v, xf[mt][1].v, hq);
                ushort4 p;
                p.x = bf16bits(fmaxf(hq[0], 0.f));
                p.y = bf16bits(fmaxf(hq[1], 0.f));
                p.z = bf16bits(fmaxf(hq[2], 0.f));
                p.w = bf16bits(fmaxf(hq[3], 0.f));
                hw[(16*mt + lr) * 18 + 4*q + lg] = *reinterpret_cast<uint2*>(&p);
            }
        }
        // GEMM2 (swapped): consume own h (intra-wave in-order DS, no barrier)
        #pragma unroll
        for (int mt = 0; mt < 2; ++mt) {
            #pragma unroll
            for (int kh = 0; kh < 2; ++kh) {
                uint2 lo = hw[(16*mt + lr) * 18 + 8*kh + 2*lg];
                uint2 hi = hw[(16*mt + lr) * 18 + 8*kh + 2*lg + 1];
                Frag a2; a2.q = make_uint4(lo.x, lo.y, hi.x, hi.y);
                #pragma unroll
                for (int nt = 0; nt < 4; ++nt) {
                    Frag qr; qr.q = *reinterpret_cast<const uint4*>(&wb[(8 + kh*4 + nt) * 512 + l*8]);
                    acc2[mt][nt] = MFMA16(qr.v, a2.v, acc2[mt][nt]);
                }
                Frag qg; qg.q = *reinterpret_cast<const uint4*>(&wb[(16 + kh) * 512 + l*8]);
                acc2[mt][4] = MFMA16(qg.v, a2.v, acc2[mt][4]);
            }
        }
    }
    __syncthreads();   // all compute done before overlaying u.o

    // ---- epilogue: row-split -> each wave writes its own rows (full sums), +bias
    #pragma unroll
    for (int mt = 0; mt < 2; ++mt)
        #pragma unroll
        for (int nt = 0; nt < 5; ++nt) {
            float4 v;
            v.x = acc2[mt][nt][0]; v.y = acc2[mt][nt][1];
            v.z = acc2[mt][nt][2]; v.w = acc2[mt][nt][3];
            float bx, by, bz, bw;
            if (nt < 4) {
                int c = 16*nt + 4*lg;
                bx = b2[c]; by = b2[c+1]; bz = b2[c+2]; bw = b2[c+3];
            } else {
                int c = 4*lg;
                bx = (c   < YD) ? b2[NK + g*YD + c  ] : 0.f;
                by = (c+1 < YD) ? b2[NK + g*YD + c+1] : 0.f;
                bz = (c+2 < YD) ? b2[NK + g*YD + c+2] : 0.f;
                bw = (c+3 < YD) ? b2[NK + g*YD + c+3] : 0.f;
            }
            v.x += bx; v.y += by; v.z += bz; v.w += bw;
            *reinterpret_cast<float4*>(&u.o[32*w + 16*mt + lr][16*nt + 4*lg]) = v;
        }
    __syncthreads();

    if (t < TS) {
        float ce_v = 0.f, mse_v = 0.f;
        if (t < nrows) {
            float m = -1e30f;
            for (int c = 0; c < NK; ++c) m = fmaxf(m, u.o[t][c]);
            float s2 = 0.f;
            for (int c = 0; c < NK; ++c) s2 += expf(u.o[t][c] - m);
            float lse = m + logf(s2);
            ce_v = lse - u.o[t][g];
            int row = rows_s[t];
            #pragma unroll
            for (int j = 0; j < YD; ++j) {
                float tr = y[row * YD + j] - centers[g * YD + j];
                float d  = tr - u.o[t][NK + j];
                mse_v += d * d;
            }
        }
        red_ce[t] = ce_v; red_mse[t] = mse_v;
    }
    __syncthreads();
    if (t == 0) {
        float sc = 0.f, sm = 0.f;
        for (int i = 0; i < TS; ++i) { sc += red_ce[i]; sm += red_mse[i]; }
        atomicAdd(&accum[0], sc);
        atomicAdd(&accum[1], sm);
    }
}

__global__ void k_final(const float* __restrict__ accum, float* __restrict__ out) {
    out[0] = accum[0] / (float)B_N + 100.f * accum[1] / ((float)B_N * (float)YD);
}

extern "C" void kernel_launch(void* const* d_in, const int* in_sizes, int n_in,
                              void* d_out, int out_size, void* d_ws, size_t ws_size,
                              hipStream_t stream) {
    const float* x       = (const float*)d_in[0];
    const float* y       = (const float*)d_in[1];
    const float* centers = (const float*)d_in[2];
    const float* W1      = (const float*)d_in[3];
    const float* b1      = (const float*)d_in[4];
    const float* W2      = (const float*)d_in[5];
    const float* b2      = (const float*)d_in[6];

    char* ws = (char*)d_ws;
    float* accum  = (float*)ws;                        // 2 f32 @ 0
    int* counts   = (int*)(ws + 256);                  // 64 ints
    int* cursor   = (int*)(ws + 768);
    int* tile_g   = (int*)(ws + 1024);                 // MAXT
    int* tile_off = (int*)(ws + 1024 + 4 * MAXT);
    int* tile_n   = (int*)(ws + 1024 + 8 * MAXT);
    char* ws2     = ws + 1024 + 12 * MAXT + 256;
    int* labels   = (int*)ws2;                               // 128 KB
    int* perm     = (int*)(ws2 + 131072);                    // 128 KB
    unsigned short* W1P = (unsigned short*)(ws2 + 262144);   // 256 KB
    unsigned short* W2P = (unsigned short*)(ws2 + 524288);   // 256 KB
    unsigned short* W2G = (unsigned short*)(ws2 + 786432);   // 4 MB

    hipMemsetAsync(ws, 0, 1024, stream);   // zero accum + counts
    k_prep   <<<LBLK + 192, 256, 0, stream>>>(y, centers, W1, b1, W2,
                                              labels, counts, W1P, W2P, W2G);
    k_scan   <<<1, 64, 0, stream>>>(counts, cursor, tile_g, tile_off, tile_n);
    k_scatter<<<B_N / 256, 256, 0, stream>>>(labels, cursor, perm);
    k_fused  <<<MAXT, 256, 0, stream>>>(x, W1P, W2P, W2G, b2, y, centers,
                                        tile_g, tile_off, tile_n, perm, accum);
    k_final  <<<1, 1, 0, stream>>>(accum, (float*)d_out);
}

// Round 17
// 70.801 us; speedup vs baseline: 1.3844x; 1.3844x over previous
//
#include <hip/hip_runtime.h>
#include <hip/hip_bf16.h>
#include <math.h>

#define B_N    32768
#define XD     60
#define YD     10
#define NK     64
#define HID    2048
#define OUTD   704   // NK + NK*YD
#define TS     64    // rows per tile
#define MAXT   576   // >= 512 full tiles + 64 partials; divisible by 8 (XCD swizzle)

#define LBLK   128   // label blocks (B/256)

typedef float f32x4_t __attribute__((ext_vector_type(4)));

#define MFMA8(a, b, c) __builtin_amdgcn_mfma_f32_16x16x32_fp8_fp8(a, b, c, 0, 0, 0)

__device__ __forceinline__ unsigned short bf16bits(float f) {
    __hip_bfloat16 h = __float2bfloat16(f);
    return *reinterpret_cast<unsigned short*>(&h);
}
__device__ __forceinline__ float bff(unsigned short b) {
    unsigned int u = ((unsigned int)b) << 16;
    return __uint_as_float(u);
}
// pack 4 floats -> 4 e4m3 bytes (RNE, saturating) via HW cvt
__device__ __forceinline__ int pk4(float a, float b, float c, float d) {
    int p = __builtin_amdgcn_cvt_pk_fp8_f32(a, b, 0, false);
    return __builtin_amdgcn_cvt_pk_fp8_f32(c, d, p, true);
}

// ---------------- merged prep: labels+counts | W1F | W2F | W2GF fp8 packs ----
// All weights pre-scaled by 16 (epilogue divides by 256) to dodge e4m3
// subnormals. Record geometry (slice f = (s,w) covers hid [128s+32w, +32)):
//   W1F: (s4w,n2) 1KB rec: lane l, byte 8ks+b = fp8(16*W1[10+32ks+8lg+b][hid16n2+lr]); k=60 row = 16*b1
//   W2F: (s4w,p)  1KB rec: byte (q&1)*8+b    = fp8(16*W2[k0+8lg+b][16q+lr]), q=2p..2p+1
//   W2GF:(g,s,w) 512B rec: byte b            = fp8(16*W2[k0+8lg+b][64+10g+lr]) (lr<10)
__global__ __launch_bounds__(256) void k_prep(const float* __restrict__ y,
                                              const float* __restrict__ centers,
                                              const float* __restrict__ W1,
                                              const float* __restrict__ b1,
                                              const float* __restrict__ W2,
                                              int* __restrict__ labels,
                                              int* __restrict__ counts,
                                              unsigned char* __restrict__ W1F,
                                              unsigned char* __restrict__ W2F,
                                              unsigned char* __restrict__ W2GF) {
    __shared__ __align__(16) char smem[40960];
    int bid = blockIdx.x, t = threadIdx.x;
    int l  = t & 63;
    int lr = l & 15;
    int lg = l >> 4;

    if (bid < LBLK) {
        float* cs = (float*)smem; float* sc = cs + 640; int* lh = (int*)(cs + 704);
        for (int i = t; i < NK * YD; i += 256) cs[i] = centers[i];
        if (t < NK) lh[t] = 0;
        __syncthreads();
        if (t < NK) { float s = 0.f; for (int j = 0; j < YD; ++j) { float v = cs[t*YD+j]; s += v*v; } sc[t] = s; }
        __syncthreads();
        int i = bid * 256 + t;
        float ly[YD]; float sy = 0.f;
        for (int j = 0; j < YD; ++j) { ly[j] = y[i*YD+j]; sy += ly[j]*ly[j]; }
        float best = 1e30f; int lab = 0;
        for (int k = 0; k < NK; ++k) {
            float dot = 0.f;
            #pragma unroll
            for (int j = 0; j < YD; ++j) dot += ly[j] * cs[k*YD+j];
            float d = sy - 2.f*dot + sc[k];
            if (d < best) { best = d; lab = k; }
        }
        labels[i] = lab;
        atomicAdd(&lh[lab], 1);
        __syncthreads();
        if (t < NK && lh[t] > 0) atomicAdd(&counts[t], lh[t]);
    } else if (bid < LBLK + 64) {
        // ---- W1F (scaled x16, b1 folded at k=60)
        int b = bid - LBLK, s = b >> 2, w = b & 3;
        unsigned short (*lds)[32] = (unsigned short(*)[32])smem;   // [k 0..63][n 0..31]
        int n0 = 128*s + 32*w;
        for (int idx = t; idx < 64*32; idx += 256) {
            int kk = idx >> 5, c = idx & 31;
            float v = (kk < XD) ? 16.f * W1[(size_t)(YD + kk) * HID + n0 + c]
                                : ((kk == XD) ? 16.f * b1[n0 + c] : 0.f);
            lds[kk][c] = bf16bits(v);
        }
        __syncthreads();
        if (t < 128) {
            int n2 = (t >> 6) & 1;
            float v[16];
            #pragma unroll
            for (int ks = 0; ks < 2; ++ks)
                #pragma unroll
                for (int bb = 0; bb < 8; ++bb)
                    v[8*ks + bb] = bff(lds[32*ks + 8*lg + bb][16*n2 + lr]);
            uint4 o;
            o.x = pk4(v[0],v[1],v[2],v[3]);   o.y = pk4(v[4],v[5],v[6],v[7]);
            o.z = pk4(v[8],v[9],v[10],v[11]); o.w = pk4(v[12],v[13],v[14],v[15]);
            *reinterpret_cast<uint4*>(&W1F[((s*4 + w)*2 + n2)*1024 + l*16]) = o;
        }
    } else if (bid < LBLK + 128) {
        // ---- W2F (logit cols, scaled x16)
        int b = bid - LBLK - 64, s = b >> 2, w = b & 3;
        unsigned short (*lds)[64] = (unsigned short(*)[64])smem;   // [k 0..31][c 0..63]
        int k0 = 128*s + 32*w;
        for (int idx = t; idx < 32*64; idx += 256) {
            int kk = idx >> 6, c = idx & 63;
            lds[kk][c] = bf16bits(16.f * W2[(size_t)(k0 + kk) * OUTD + c]);
        }
        __syncthreads();
        int q = t >> 6;   // nt 0..3
        float v[8];
        #pragma unroll
        for (int bb = 0; bb < 8; ++bb) v[bb] = bff(lds[8*lg + bb][16*q + lr]);
        uint2 o;
        o.x = pk4(v[0],v[1],v[2],v[3]); o.y = pk4(v[4],v[5],v[6],v[7]);
        *reinterpret_cast<uint2*>(&W2F[((s*4 + w)*2 + (q >> 1))*1024 + l*16 + (q & 1)*8]) = o;
    } else {
        // ---- W2GF (group cols, scaled x16)
        int b = bid - LBLK - 128, s = b >> 2, w = b & 3;
        unsigned short (*lds)[640] = (unsigned short(*)[640])smem;
        int k0 = 128*s + 32*w;
        for (int idx = t; idx < 32*640; idx += 256) {
            int kk = idx / 640, c = idx - kk*640;
            lds[kk][c] = bf16bits(16.f * W2[(size_t)(k0 + kk) * OUTD + NK + c]);
        }
        __syncthreads();
        for (int g = t >> 6; g < 64; g += 4) {
            float v[8];
            #pragma unroll
            for (int bb = 0; bb < 8; ++bb)
                v[bb] = (lr < YD) ? bff(lds[8*lg + bb][10*g + lr]) : 0.f;
            uint2 o;
            o.x = pk4(v[0],v[1],v[2],v[3]); o.y = pk4(v[4],v[5],v[6],v[7]);
            *reinterpret_cast<uint2*>(&W2GF[(((g*16 + s)*4 + w) << 9) + l*8]) = o;
        }
    }
}

// ---------------- wave-parallel scan + tile-descriptor build ----------
__global__ void k_scan(const int* __restrict__ counts, int* __restrict__ cursor,
                       int* __restrict__ tile_g, int* __restrict__ tile_off,
                       int* __restrict__ tile_n) {
    int t = threadIdx.x;
    int c = counts[t];
    int ntm = (c + TS - 1) / TS;
    int sc = c, st = ntm;
    #pragma unroll
    for (int d = 1; d < 64; d <<= 1) {
        int vc = __shfl_up(sc, d);
        int vt = __shfl_up(st, d);
        if (t >= d) { sc += vc; st += vt; }
    }
    int off   = sc - c;
    int tbase = st - ntm;
    cursor[t] = off;
    for (int i = 0; i < ntm; ++i) {
        tile_g[tbase + i]   = t;
        tile_off[tbase + i] = off + TS * i;
        tile_n[tbase + i]   = min(TS, c - TS * i);
    }
    int total = __shfl(st, 63);
    for (int i = total + t; i < MAXT; i += 64) tile_n[i] = 0;
}

// ---------------- scatter ----------
__global__ __launch_bounds__(256) void k_scatter(const int* __restrict__ labels,
                                                 int* __restrict__ cursor,
                                                 int* __restrict__ perm) {
    __shared__ int lh[NK], lbase[NK];
    int t = threadIdx.x;
    if (t < NK) lh[t] = 0;
    __syncthreads();
    int i = blockIdx.x * 256 + t;
    int lab = labels[i];
    int rank = atomicAdd(&lh[lab], 1);
    __syncthreads();
    if (t < NK && lh[t] > 0) lbase[t] = atomicAdd(&cursor[t], lh[t]);
    __syncthreads();
    perm[lbase[lab] + rank] = i;
}

// per-slab weight registers: 5 loads, 18 VGPRs per set
struct WR { uint4 w0, w1, q0, q1; uint2 qg; };

__device__ __forceinline__ void loadw(WR& r, int s_,
                                      const unsigned char* __restrict__ W1F,
                                      const unsigned char* __restrict__ W2F,
                                      const unsigned char* __restrict__ W2GF,
                                      int g, int w, int l) {
    int f1 = (s_*4 + w)*2048 + l*16;
    r.w0 = *reinterpret_cast<const uint4*>(W1F + f1);
    r.w1 = *reinterpret_cast<const uint4*>(W1F + f1 + 1024);
    r.q0 = *reinterpret_cast<const uint4*>(W2F + f1);
    r.q1 = *reinterpret_cast<const uint4*>(W2F + f1 + 1024);
    r.qg = *reinterpret_cast<const uint2*>(W2GF + (((g*16 + s_)*4 + w) << 9) + l*8);
}

union U4 { uint4 q; long long l2[2]; };
union U2 { uint2 u; long long ll; };

__device__ __forceinline__ void slab_body(const WR& r,
                                          const U2 (&xf)[4][2], f32x4_t (&acc2)[4][5],
                                          unsigned char* hw, int lr, int lg) {
    U4 w0, w1, q0, q1; w0.q = r.w0; w1.q = r.w1; q0.q = r.q0; q1.q = r.q1;
    U2 qg; qg.u = r.qg;
    // GEMM1 (swapped): wave's 32 hid cols; relu+fp8-pack -> per-wave h scratch
    #pragma unroll
    for (int mt = 0; mt < 4; ++mt) {
        f32x4_t h0 = {0.f, 0.f, 0.f, 0.f}, h1 = {0.f, 0.f, 0.f, 0.f};
        h0 = MFMA8(w0.l2[0], xf[mt][0].ll, h0);
        h0 = MFMA8(w0.l2[1], xf[mt][1].ll, h0);
        h1 = MFMA8(w1.l2[0], xf[mt][0].ll, h1);
        h1 = MFMA8(w1.l2[1], xf[mt][1].ll, h1);
        unsigned char* hrow = hw + (16*mt + lr) * 40;
        *reinterpret_cast<unsigned int*>(hrow + 4*lg) =
            (unsigned int)pk4(fmaxf(h0[0],0.f), fmaxf(h0[1],0.f), fmaxf(h0[2],0.f), fmaxf(h0[3],0.f));
        *reinterpret_cast<unsigned int*>(hrow + 16 + 4*lg) =
            (unsigned int)pk4(fmaxf(h1[0],0.f), fmaxf(h1[1],0.f), fmaxf(h1[2],0.f), fmaxf(h1[3],0.f));
    }
    // GEMM2 (swapped, K-split): consume own hid slice (intra-wave in-order DS)
    #pragma unroll
    for (int mt = 0; mt < 4; ++mt) {
        U2 a2; a2.u = *reinterpret_cast<const uint2*>(hw + (16*mt + lr) * 40 + 8*lg);
        acc2[mt][0] = MFMA8(q0.l2[0], a2.ll, acc2[mt][0]);
        acc2[mt][1] = MFMA8(q0.l2[1], a2.ll, acc2[mt][1]);
        acc2[mt][2] = MFMA8(q1.l2[0], a2.ll, acc2[mt][2]);
        acc2[mt][3] = MFMA8(q1.l2[1], a2.ll, acc2[mt][3]);
        acc2[mt][4] = MFMA8(qg.ll,    a2.ll, acc2[mt][4]);
    }
}

// ---------------- fused: one 64-row single-group tile per block, 4 waves.
// fp8 e4m3 weights/activations (16x16x32 fp8 MFMA, same fragment geometry as
// bf16). 5 weight loads/slab (paired records); depth-2 prefetch (18-reg sets)
// pinned with sched_barrier(0). Weights pre-scaled x16 -> epilogue /256.
__global__ __launch_bounds__(256, 2) void k_fused(const float* __restrict__ x,
                                                  const unsigned char* __restrict__ W1F,
                                                  const unsigned char* __restrict__ W2F,
                                                  const unsigned char* __restrict__ W2GF,
                                                  const float* __restrict__ b2,
                                                  const float* __restrict__ y,
                                                  const float* __restrict__ centers,
                                                  const int* __restrict__ tile_g,
                                                  const int* __restrict__ tile_off,
                                                  const int* __restrict__ tile_n,
                                                  const int* __restrict__ perm,
                                                  float* __restrict__ accum) {
    __shared__ __align__(16) union {
        struct { unsigned char x[TS][80]; unsigned char h[4][TS][40]; } a;  // 5120 + 10240 B
        float o[TS][84];                                                    // 21504 B
    } u;
    __shared__ int   rows_s[TS];
    __shared__ float red_ce[TS], red_mse[TS];

    int phys = blockIdx.x, t = threadIdx.x;
    int bid  = (phys & 7) * (MAXT / 8) + (phys >> 3);   // XCD chunk swizzle (bijective)
    int nrows = tile_n[bid];
    if (nrows == 0) return;
    int g   = tile_g[bid];
    int off = tile_off[bid];

    int w  = t >> 6;
    int l  = t & 63;
    int lr = l & 15;
    int lg = l >> 4;

    if (t < TS) rows_s[t] = (t < nrows) ? perm[off + t] : -1;
    __syncthreads();

    // gather x rows -> LDS fp8; col 60 = 1.0 (bias lane, e4m3 0x38), 61..79 = 0
    {
        int c4 = t & 15;
        #pragma unroll
        for (int it = 0; it < 4; ++it) {
            int r = 16 * it + (t >> 4);
            int row = rows_s[r];
            if (c4 < 15) {
                int pk = 0;
                if (row >= 0) {
                    float4 v = *reinterpret_cast<const float4*>(&x[(size_t)row * XD + 4 * c4]);
                    pk = pk4(v.x, v.y, v.z, v.w);
                }
                *reinterpret_cast<unsigned int*>(&u.a.x[r][4 * c4]) = (unsigned int)pk;
            } else {
                *reinterpret_cast<unsigned int*>(&u.a.x[r][60]) = (row >= 0) ? 0x00000038u : 0u;
                uint4 z = {0, 0, 0, 0};
                *reinterpret_cast<uint4*>(&u.a.x[r][64]) = z;
            }
        }
    }
    __syncthreads();   // the ONLY barrier before the epilogue

    U2 xf[4][2];
    #pragma unroll
    for (int mt = 0; mt < 4; ++mt)
        #pragma unroll
        for (int ks = 0; ks < 2; ++ks)
            xf[mt][ks].u = *reinterpret_cast<const uint2*>(&u.a.x[16*mt + lr][32*ks + 8*lg]);

    f32x4_t acc2[4][5];
    #pragma unroll
    for (int mt = 0; mt < 4; ++mt)
        #pragma unroll
        for (int nt = 0; nt < 5; ++nt) acc2[mt][nt] = (f32x4_t){0.f, 0.f, 0.f, 0.f};

    unsigned char* hw = &u.a.h[w][0][0];

    // depth-2 pipeline, order pinned by sched_barrier(0)
    WR rA, rB;
    loadw(rA, 0, W1F, W2F, W2GF, g, w, l);
    #pragma unroll 1
    for (int s = 0; s < HID / 128; s += 2) {
        __builtin_amdgcn_sched_barrier(0);
        loadw(rB, s + 1, W1F, W2F, W2GF, g, w, l);
        __builtin_amdgcn_sched_barrier(0);
        slab_body(rA, xf, acc2, hw, lr, lg);
        __builtin_amdgcn_sched_barrier(0);
        loadw(rA, (s + 2 < 16) ? s + 2 : 0, W1F, W2F, W2GF, g, w, l);
        __builtin_amdgcn_sched_barrier(0);
        slab_body(rB, xf, acc2, hw, lr, lg);
    }
    __syncthreads();   // all x/h use done before overlaying u.o

    // epilogue: sum 4 K-partials (x 1/256 for the 16x16 weight prescale), bias in phase 0
    const float inv = 1.f / 256.f;
    for (int wv = 0; wv < 4; ++wv) {
        if (w == wv) {
            #pragma unroll
            for (int mt = 0; mt < 4; ++mt)
                #pragma unroll
                for (int nt = 0; nt < 5; ++nt) {
                    float4 v;
                    v.x = acc2[mt][nt][0] * inv; v.y = acc2[mt][nt][1] * inv;
                    v.z = acc2[mt][nt][2] * inv; v.w = acc2[mt][nt][3] * inv;
                    float4* pp = reinterpret_cast<float4*>(&u.o[16*mt + lr][16*nt + 4*lg]);
                    if (wv == 0) {
                        float bx, by, bz, bw;
                        if (nt < 4) {
                            int c = 16*nt + 4*lg;
                            bx = b2[c]; by = b2[c+1]; bz = b2[c+2]; bw = b2[c+3];
                        } else {
                            int c = 4*lg;
                            bx = (c   < YD) ? b2[NK + g*YD + c  ] : 0.f;
                            by = (c+1 < YD) ? b2[NK + g*YD + c+1] : 0.f;
                            bz = (c+2 < YD) ? b2[NK + g*YD + c+2] : 0.f;
                            bw = (c+3 < YD) ? b2[NK + g*YD + c+3] : 0.f;
                        }
                        v.x += bx; v.y += by; v.z += bz; v.w += bw;
                        *pp = v;
                    } else {
                        float4 cur = *pp;
                        cur.x += v.x; cur.y += v.y; cur.z += v.z; cur.w += v.w;
                        *pp = cur;
                    }
                }
        }
        __syncthreads();
    }

    if (t < TS) {
        float ce_v = 0.f, mse_v = 0.f;
        if (t < nrows) {
            float m = -1e30f;
            for (int c = 0; c < NK; ++c) m = fmaxf(m, u.o[t][c]);
            float s2 = 0.f;
            for (int c = 0; c < NK; ++c) s2 += expf(u.o[t][c] - m);
            float lse = m + logf(s2);
            ce_v = lse - u.o[t][g];
            int row = rows_s[t];
            #pragma unroll
            for (int j = 0; j < YD; ++j) {
                float tr = y[row * YD + j] - centers[g * YD + j];
                float d  = tr - u.o[t][NK + j];
                mse_v += d * d;
            }
        }
        red_ce[t] = ce_v; red_mse[t] = mse_v;
    }
    __syncthreads();
    if (t == 0) {
        float sc = 0.f, sm = 0.f;
        for (int i = 0; i < TS; ++i) { sc += red_ce[i]; sm += red_mse[i]; }
        atomicAdd(&accum[0], sc);
        atomicAdd(&accum[1], sm);
    }
}

__global__ void k_final(const float* __restrict__ accum, float* __restrict__ out) {
    out[0] = accum[0] / (float)B_N + 100.f * accum[1] / ((float)B_N * (float)YD);
}

extern "C" void kernel_launch(void* const* d_in, const int* in_sizes, int n_in,
                              void* d_out, int out_size, void* d_ws, size_t ws_size,
                              hipStream_t stream) {
    const float* x       = (const float*)d_in[0];
    const float* y       = (const float*)d_in[1];
    const float* centers = (const float*)d_in[2];
    const float* W1      = (const float*)d_in[3];
    const float* b1      = (const float*)d_in[4];
    const float* W2      = (const float*)d_in[5];
    const float* b2      = (const float*)d_in[6];

    char* ws = (char*)d_ws;
    float* accum  = (float*)ws;                        // 2 f32 @ 0
    int* counts   = (int*)(ws + 256);                  // 64 ints
    int* cursor   = (int*)(ws + 768);
    int* tile_g   = (int*)(ws + 1024);                 // MAXT
    int* tile_off = (int*)(ws + 1024 + 4 * MAXT);
    int* tile_n   = (int*)(ws + 1024 + 8 * MAXT);
    char* ws2     = ws + 1024 + 12 * MAXT + 256;
    int* labels   = (int*)ws2;                                   // 128 KB
    int* perm     = (int*)(ws2 + 131072);                        // 128 KB
    unsigned char* W1F  = (unsigned char*)(ws2 + 262144);        // 128 KB
    unsigned char* W2F  = (unsigned char*)(ws2 + 393216);        // 128 KB
    unsigned char* W2GF = (unsigned char*)(ws2 + 524288);        // 2 MB

    hipMemsetAsync(ws, 0, 1024, stream);   // zero accum + counts
    k_prep   <<<LBLK + 192, 256, 0, stream>>>(y, centers, W1, b1, W2,
                                              labels, counts, W1F, W2F, W2GF);
    k_scan   <<<1, 64, 0, stream>>>(counts, cursor, tile_g, tile_off, tile_n);
    k_scatter<<<B_N / 256, 256, 0, stream>>>(labels, cursor, perm);
    k_fused  <<<MAXT, 256, 0, stream>>>(x, W1F, W2F, W2GF, b2, y, centers,
                                        tile_g, tile_off, tile_n, perm, accum);
    k_final  <<<1, 1, 0, stream>>>(accum, (float*)d_out);
}